// Round 7
// baseline (101.652 us; speedup 1.0000x reference)
//
#include <hip/hip_runtime.h>
#include <stdint.h>

// Problem constants
#define D       32
#define B       2048
#define M       65536
#define STRIPS  1024          // M / 64 rows per strip
#define CHUNKS  4             // batch chunks (one per wave in a screen block)
#define CHCOLS  (B / CHUNKS)  // 512 cols per chunk
#define NTILES  (CHCOLS / 16) // 32 16-col tiles per wave-job
#define SGROUPS 32            // strip groups
#define SPERG   (STRIPS / SGROUPS)  // 32 strips per group
#define MARGIN  0.15f         // ~2x worst-case 1-term fp16 screen error (~0.08)

typedef _Float16 half8  __attribute__((ext_vector_type(8)));
typedef _Float16 half4v __attribute__((ext_vector_type(4)));
typedef float    floatx4 __attribute__((ext_vector_type(4)));

// ---------------------------------------------------------------------------
// fast-path ws layout (16B aligned):
//   [0,     128K)     x_hi  _Float16[B*D]
//   [128K,  128K+8M)  pmax  uint32[STRIPS*B]  (sortable screened max per strip,col)
//   [+8M,   +256K)    gmax  uint32[SGROUPS*B] (group max via atomicMax; prep zeroes)
// ---------------------------------------------------------------------------

__device__ __forceinline__ uint32_t f32_sortable(float f) {
    uint32_t u = __float_as_uint(f);
    u ^= (uint32_t)((int32_t)u >> 31) | 0x80000000u;
    return u;
}
__device__ __forceinline__ float sort_decode(uint32_t u) {
    uint32_t m = (u & 0x80000000u) ? (u ^ 0x80000000u) : ~u;
    return __uint_as_float(m);
}

// ============ prep: x -> fp16 hi + zero gmax ===============================
// 64 blocks x 256. Each thread converts 4 x values and zeroes 4 gmax entries
// (16384 threads x 4 = 65536 = SGROUPS*B). Stream order guarantees gmax is
// zero before screen's atomics.
__global__ void som_prep_kernel(const float* __restrict__ x,
                                _Float16* __restrict__ xh,
                                uint32_t* __restrict__ gmax) {
    const int tid = blockIdx.x * 256 + threadIdx.x;
    const int i   = tid * 4;
    float4 v = *(const float4*)(x + i);
    half4v h;
    h[0] = (_Float16)v.x; h[1] = (_Float16)v.y;
    h[2] = (_Float16)v.z; h[3] = (_Float16)v.w;
    *(half4v*)(xh + i) = h;
    ((uint4*)gmax)[tid] = make_uint4(0u, 0u, 0u, 0u);
}

// ============ screen: 1-term fp16 MFMA over 2 strips per block =============
// Block owns strips (2s, 2s+1) — same group always (pairs never straddle a
// 32-strip boundary). bh loaded once per tile feeds 8 MFMAs (2x the
// MFMA:load ratio of 1-strip blocks; halves x_hi L2 traffic). Exact fp32
// -0.5||w||^2 rides in C init. Epilogue: 2 fmax trees + quad butterflies,
// 2 pmax stores + 1 atomicMax into gmax.
__global__ __launch_bounds__(256, 2)
void som_screen_kernel(const float* __restrict__ w,
                       const _Float16* __restrict__ x_hi,
                       uint32_t* __restrict__ pmax,
                       uint32_t* __restrict__ gmax) {
    const int sA   = blockIdx.x * 2;        // strips sA, sA+1 (blockIdx < 512)
    const int wv   = threadIdx.x >> 6;      // chunk 0..3
    const int lane = threadIdx.x & 63;
    const int q    = lane >> 4;             // quad 0..3
    const int j    = lane & 15;

    // A-frags for both strips: A[m=lane&15][k=q*8+kk]; 4 row-tiles x 2 strips.
    half8   a_hi[2][4];
    floatx4 init[2][4];
#pragma unroll
    for (int p = 0; p < 2; p++) {
        float nrm[4];
#pragma unroll
        for (int t = 0; t < 4; t++) {
            const float* wp = w + (size_t)((sA + p) * 64 + t * 16 + j) * D + q * 8;
            float4 f0 = ((const float4*)wp)[0];
            float4 f1 = ((const float4*)wp)[1];
            float f[8] = {f0.x, f0.y, f0.z, f0.w, f1.x, f1.y, f1.z, f1.w};
            float sq = 0.0f;
#pragma unroll
            for (int k = 0; k < 8; k++) {
                a_hi[p][t][k] = (_Float16)f[k];
                sq = fmaf(f[k], f[k], sq);
            }
            sq += __shfl_xor(sq, 16);
            sq += __shfl_xor(sq, 32);
            nrm[t] = sq;
        }
#pragma unroll
        for (int t = 0; t < 4; t++)
#pragma unroll
            for (int r = 0; r < 4; r++)
                init[p][t][r] = -0.5f * __shfl(nrm[t], q * 4 + r);
    }

    uint32_t* pm0 = pmax + (size_t)sA * B;
    uint32_t* pm1 = pmax + (size_t)(sA + 1) * B;
    uint32_t* gm  = gmax + (size_t)(sA >> 5) * B;   // group = strip/32

    for (int it = 0; it < NTILES; it++) {
        const int col = wv * CHCOLS + it * 16 + j;
        const half8 bh = *(const half8*)(x_hi + (size_t)col * D + q * 8);

        floatx4 acc[2][4];
#pragma unroll
        for (int p = 0; p < 2; p++)
#pragma unroll
            for (int t = 0; t < 4; t++)
                acc[p][t] = __builtin_amdgcn_mfma_f32_16x16x32_f16(
                    a_hi[p][t], bh, init[p][t], 0, 0, 0);

        float best[2];
#pragma unroll
        for (int p = 0; p < 2; p++) {
            float b0 = fmaxf(fmaxf(acc[p][0][0], acc[p][0][1]), fmaxf(acc[p][0][2], acc[p][0][3]));
            float b1 = fmaxf(fmaxf(acc[p][1][0], acc[p][1][1]), fmaxf(acc[p][1][2], acc[p][1][3]));
            float b2 = fmaxf(fmaxf(acc[p][2][0], acc[p][2][1]), fmaxf(acc[p][2][2], acc[p][2][3]));
            float b3 = fmaxf(fmaxf(acc[p][3][0], acc[p][3][1]), fmaxf(acc[p][3][2], acc[p][3][3]));
            float bb = fmaxf(fmaxf(b0, b1), fmaxf(b2, b3));
            bb = fmaxf(bb, __shfl_xor(bb, 16));
            bb = fmaxf(bb, __shfl_xor(bb, 32));
            best[p] = bb;
        }

        if (lane < 16) {
            const uint32_t u0 = f32_sortable(best[0]);
            const uint32_t u1 = f32_sortable(best[1]);
            pm0[col] = u0;
            pm1[col] = u1;
            atomicMax(&gm[col], u0 > u1 ? u0 : u1);
        }
    }
}

// ============ final: margin-protected exact fp32 rescore + gather ==========
// One wave per col. v1 = max over 32 group maxes; thresh = v1 - MARGIN.
// Every group with gmax >= thresh gets its 32 strips' pmax scanned; every
// strip >= thresh is rescored in exact fp32 (covers the winner). Lowest-index
// tie-break via (score,~row) key.
__device__ __forceinline__ void rescore_strip(int strip, int lane,
                                              const float* __restrict__ w,
                                              const float* xr,
                                              uint64_t& best) {
    const int row = strip * 64 + lane;
    const float* wr = w + (size_t)row * D;
    float4 w0 = ((const float4*)wr)[0];
    float4 w1 = ((const float4*)wr)[1];
    float4 w2 = ((const float4*)wr)[2];
    float4 w3 = ((const float4*)wr)[3];
    float4 w4 = ((const float4*)wr)[4];
    float4 w5 = ((const float4*)wr)[5];
    float4 w6 = ((const float4*)wr)[6];
    float4 w7 = ((const float4*)wr)[7];
    const float wf[32] = {w0.x,w0.y,w0.z,w0.w, w1.x,w1.y,w1.z,w1.w,
                          w2.x,w2.y,w2.z,w2.w, w3.x,w3.y,w3.z,w3.w,
                          w4.x,w4.y,w4.z,w4.w, w5.x,w5.y,w5.z,w5.w,
                          w6.x,w6.y,w6.z,w6.w, w7.x,w7.y,w7.z,w7.w};
    float acc = 0.0f, nn = 0.0f;
#pragma unroll
    for (int i = 0; i < D; i++) {
        acc = fmaf(xr[i], wf[i], acc);
        nn  = fmaf(wf[i], wf[i], nn);
    }
    const float score = acc - 0.5f * nn;
    const uint64_t key = ((uint64_t)f32_sortable(score) << 32)
                       | (uint32_t)(~(uint32_t)row);
    if (key > best) best = key;
}

__global__ __launch_bounds__(256)
void som_final_kernel(const uint32_t* __restrict__ gmax,
                      const uint32_t* __restrict__ pmax,
                      const float* __restrict__ x,
                      const float* __restrict__ w,
                      const float* __restrict__ grid_flat,
                      float* __restrict__ out) {
    const int wv   = threadIdx.x >> 6;
    const int lane = threadIdx.x & 63;
    const int col  = blockIdx.x * 4 + wv;            // gridDim.x = B/4

    // group maxes: lane g < 32 holds group g's sortable max
    const uint32_t g = (lane < SGROUPS) ? gmax[(size_t)lane * B + col] : 0u;
    uint32_t vmax = g;
    vmax = max(vmax, (uint32_t)__shfl_xor((int)vmax,  1));
    vmax = max(vmax, (uint32_t)__shfl_xor((int)vmax,  2));
    vmax = max(vmax, (uint32_t)__shfl_xor((int)vmax,  4));
    vmax = max(vmax, (uint32_t)__shfl_xor((int)vmax,  8));
    vmax = max(vmax, (uint32_t)__shfl_xor((int)vmax, 16));
    vmax = max(vmax, (uint32_t)__shfl_xor((int)vmax, 32));
    const uint32_t thresh_u = f32_sortable(sort_decode(vmax) - MARGIN);

    // x col into registers (wave-uniform values)
    float xr[D];
    const float4* xp = (const float4*)(x + (size_t)col * D);
#pragma unroll
    for (int i = 0; i < D / 4; i++) {
        float4 v = xp[i];
        xr[4*i+0] = v.x; xr[4*i+1] = v.y; xr[4*i+2] = v.z; xr[4*i+3] = v.w;
    }

    uint64_t best = 0;
    unsigned long long gmask = __ballot((lane < SGROUPS) && (g >= thresh_u));
    while (gmask) {
        const int gi = __ffsll(gmask) - 1;
        gmask &= gmask - 1;
        uint32_t u = 0;
        if (lane < SPERG) u = pmax[(size_t)(gi * SPERG + lane) * B + col];
        unsigned long long smask = __ballot((lane < SPERG) && (u >= thresh_u));
        while (smask) {
            const int sl = __ffsll(smask) - 1;
            smask &= smask - 1;
            rescore_strip(gi * SPERG + sl, lane, w, xr, best);
        }
    }

    // wave argmax over keys (covers all rescored rows)
    {
        uint64_t o;
        o = (uint64_t)__shfl_xor((long long)best,  1); if (o > best) best = o;
        o = (uint64_t)__shfl_xor((long long)best,  2); if (o > best) best = o;
        o = (uint64_t)__shfl_xor((long long)best,  4); if (o > best) best = o;
        o = (uint64_t)__shfl_xor((long long)best,  8); if (o > best) best = o;
        o = (uint64_t)__shfl_xor((long long)best, 16); if (o > best) best = o;
        o = (uint64_t)__shfl_xor((long long)best, 32); if (o > best) best = o;
    }
    if (lane == 0) {
        const uint32_t idx = ~(uint32_t)best;
        ((float2*)out)[col] = ((const float2*)grid_flat)[idx];
    }
}

// ===========================================================================
// Fallback path (round-1, proven correct, needs only 2.36 MB ws)
// ===========================================================================
#define MTILES  128
#define MTILE   (M / MTILES)
#define BTILE   256

__global__ void som_wnorm_kernel(const float* __restrict__ w,
                                 float* __restrict__ wnorm) {
    int t   = blockIdx.x * blockDim.x + threadIdx.x;
    int row = t >> 2;
    int j   = t & 3;
    const float4* p = (const float4*)(w + (size_t)row * D) + j * 2;
    float4 a = p[0];
    float4 b4 = p[1];
    float s = a.x * a.x + a.y * a.y + a.z * a.z + a.w * a.w
            + b4.x * b4.x + b4.y * b4.y + b4.z * b4.z + b4.w * b4.w;
    s += __shfl_xor(s, 1);
    s += __shfl_xor(s, 2);
    if (j == 0) wnorm[row] = 0.5f * s;
}

__global__ __launch_bounds__(BTILE, 8)
void som_score_kernel(const float* __restrict__ x,
                      const float* __restrict__ w,
                      const float* __restrict__ wnorm,
                      float* __restrict__ pscore,
                      int*   __restrict__ pidx) {
    const int bt = blockIdx.x;
    const int mt = blockIdx.y;
    const int b  = bt * BTILE + threadIdx.x;

    float xr[D];
    const float4* xp = (const float4*)(x + (size_t)b * D);
#pragma unroll
    for (int i = 0; i < D / 4; i++) {
        float4 v = xp[i];
        xr[4 * i + 0] = v.x; xr[4 * i + 1] = v.y;
        xr[4 * i + 2] = v.z; xr[4 * i + 3] = v.w;
    }

    const int m0 = mt * MTILE;
    float best = -3.0e38f;
    int   bidx = m0;
#pragma unroll 2
    for (int mm = 0; mm < MTILE; mm++) {
        const int m = m0 + mm;
        const float* __restrict__ wr = w + (size_t)m * D;
        float acc = 0.0f;
#pragma unroll
        for (int i = 0; i < D; i++) acc = fmaf(xr[i], wr[i], acc);
        const float score = acc - wnorm[m];
        if (score > best) { best = score; bidx = m; }
    }
    pscore[(size_t)b * MTILES + mt] = best;
    pidx  [(size_t)b * MTILES + mt] = bidx;
}

__global__ void som_reduce_kernel(const float* __restrict__ pscore,
                                  const int*   __restrict__ pidx,
                                  const float* __restrict__ grid_flat,
                                  float* __restrict__ out) {
    const int b = blockIdx.x * blockDim.x + threadIdx.x;
    const float* ps = pscore + (size_t)b * MTILES;
    const int*   pi = pidx   + (size_t)b * MTILES;
    float best = -3.0e38f;
    int   bidx = 0x7fffffff;
#pragma unroll 4
    for (int t = 0; t < MTILES; t++) {
        const float s  = ps[t];
        const int   id = pi[t];
        if (s > best || (s == best && id < bidx)) { best = s; bidx = id; }
    }
    ((float2*)out)[b] = ((const float2*)grid_flat)[bidx];
}

// ===========================================================================
extern "C" void kernel_launch(void* const* d_in, const int* in_sizes, int n_in,
                              void* d_out, int out_size, void* d_ws, size_t ws_size,
                              hipStream_t stream) {
    const float* x         = (const float*)d_in[0];   // [B, D]
    const float* grid_flat = (const float*)d_in[1];   // [1, M, 2]
    const float* w         = (const float*)d_in[2];   // [1, M, D]
    float* out = (float*)d_out;                       // [B, 2]

    char* ws = (char*)d_ws;
    const size_t XH_OFF = 0;
    const size_t PM_OFF = XH_OFF + (size_t)B * D * sizeof(_Float16);      // 128K
    const size_t GM_OFF = PM_OFF + (size_t)STRIPS * B * sizeof(uint32_t); // +8M
    const size_t NEED   = GM_OFF + (size_t)SGROUPS * B * sizeof(uint32_t);

    if (ws_size >= NEED) {
        _Float16* x_hi = (_Float16*)(ws + XH_OFF);
        uint32_t* pmax = (uint32_t*)(ws + PM_OFF);
        uint32_t* gmax = (uint32_t*)(ws + GM_OFF);

        som_prep_kernel<<<(B * D / 4) / 256, 256, 0, stream>>>(x, x_hi, gmax);
        som_screen_kernel<<<STRIPS / 2, 256, 0, stream>>>(w, x_hi, pmax, gmax);
        som_final_kernel<<<B / 4, 256, 0, stream>>>(gmax, pmax, x, w, grid_flat, out);
    } else {
        float* wnorm  = (float*)d_ws;
        float* pscore = wnorm + M;
        int*   pidx   = (int*)(pscore + (size_t)B * MTILES);

        som_wnorm_kernel<<<(M * 4) / 256, 256, 0, stream>>>(w, wnorm);
        dim3 grid1(B / BTILE, MTILES);
        som_score_kernel<<<grid1, BTILE, 0, stream>>>(x, w, wnorm, pscore, pidx);
        som_reduce_kernel<<<B / 256, 256, 0, stream>>>(pscore, pidx, grid_flat, out);
    }
}

// Round 8
// 98.399 us; speedup vs baseline: 1.0330x; 1.0330x over previous
//
#include <hip/hip_runtime.h>
#include <stdint.h>

// Problem constants
#define D       32
#define B       2048
#define M       65536
#define STRIPS  1024          // M / 64 rows per strip
#define CHUNKS  4             // batch chunks (one per wave in a screen block)
#define CHCOLS  (B / CHUNKS)  // 512 cols per chunk
#define NTILES  (CHCOLS / 16) // 32 16-col tiles per wave-job
#define SGROUPS 32            // strip groups in reduce1
#define SPERG   (STRIPS / SGROUPS)  // 32 strips per group
#define MARGIN  0.15f         // ~2x worst-case 1-term fp16 screen error (~0.08)

typedef _Float16 half8  __attribute__((ext_vector_type(8)));
typedef _Float16 half4v __attribute__((ext_vector_type(4)));
typedef float    floatx4 __attribute__((ext_vector_type(4)));

// ---------------------------------------------------------------------------
// Round-6 configuration (best measured: 99.6 us; rounds 4/6/7 all within
// noise at 99.6-101.7 — harness reset floor ~85 us dominates). Pipeline:
//   prep    : x -> fp16 (128 KB)
//   screen  : 1-term fp16 MFMA, exact fp32 -0.5||w||^2 in C init,
//             per-(strip,col) screened max -> pmax (8 MB)
//   reduce1 : coalesced group max (32 strips/group) -> s2
//   final   : margin-protected exact fp32 rescore of all strips within
//             MARGIN of v1 + grid gather.  MARGIN >= 2x worst-case screen
//             error bound => exact BMU (absmax 0.0 in rounds 5-7).
//
// fast-path ws layout (16B aligned):
//   [0,     128K)     x_hi  _Float16[B*D]
//   [128K,  128K+8M)  pmax  uint32[STRIPS*B]
//   [+8M,   +512K)    s2    uint64[SGROUPS*B]
// ---------------------------------------------------------------------------

__device__ __forceinline__ uint32_t f32_sortable(float f) {
    uint32_t u = __float_as_uint(f);
    u ^= (uint32_t)((int32_t)u >> 31) | 0x80000000u;
    return u;
}
__device__ __forceinline__ float sort_decode(uint32_t u) {
    uint32_t m = (u & 0x80000000u) ? (u ^ 0x80000000u) : ~u;
    return __uint_as_float(m);
}

// ============ prep: x -> fp16 hi only ======================================
__global__ void som_prep_kernel(const float* __restrict__ x,
                                _Float16* __restrict__ xh) {
    int i = (blockIdx.x * 256 + threadIdx.x) * 4;   // 64 blocks
    float4 v = *(const float4*)(x + i);
    half4v h;
    h[0] = (_Float16)v.x; h[1] = (_Float16)v.y;
    h[2] = (_Float16)v.z; h[3] = (_Float16)v.w;
    *(half4v*)(xh + i) = h;
}

// ============ screen: 1-term fp16 MFMA, per-(strip,col) max ================
__global__ __launch_bounds__(256, 4)
void som_screen_kernel(const float* __restrict__ w,
                       const _Float16* __restrict__ x_hi,
                       uint32_t* __restrict__ pmax) {
    const int s    = blockIdx.x;            // strip 0..1023
    const int wv   = threadIdx.x >> 6;      // chunk 0..3
    const int lane = threadIdx.x & 63;
    const int q    = lane >> 4;             // quad 0..3
    const int j    = lane & 15;

    // A-frags: A[m=lane&15][k=q*8+kk]; 4 row-tiles cover 64 rows.
    half8 a_hi[4];
    float nrm[4];
#pragma unroll
    for (int t = 0; t < 4; t++) {
        const float* wp = w + (size_t)(s * 64 + t * 16 + j) * D + q * 8;
        float4 f0 = ((const float4*)wp)[0];
        float4 f1 = ((const float4*)wp)[1];
        float f[8] = {f0.x, f0.y, f0.z, f0.w, f1.x, f1.y, f1.z, f1.w};
        float sq = 0.0f;
#pragma unroll
        for (int k = 0; k < 8; k++) {
            a_hi[t][k] = (_Float16)f[k];
            sq = fmaf(f[k], f[k], sq);
        }
        sq += __shfl_xor(sq, 16);
        sq += __shfl_xor(sq, 32);
        nrm[t] = sq;
    }

    // C init = -0.5*||w_row||^2 (row = t*16 + q*4 + r)
    floatx4 init[4];
#pragma unroll
    for (int t = 0; t < 4; t++)
#pragma unroll
        for (int r = 0; r < 4; r++)
            init[t][r] = -0.5f * __shfl(nrm[t], q * 4 + r);

    uint32_t* pm = pmax + (size_t)s * B;

#pragma unroll 2
    for (int it = 0; it < NTILES; it++) {
        const int col = wv * CHCOLS + it * 16 + j;
        const half8 bh = *(const half8*)(x_hi + (size_t)col * D + q * 8);

        floatx4 acc[4];
#pragma unroll
        for (int t = 0; t < 4; t++)
            acc[t] = __builtin_amdgcn_mfma_f32_16x16x32_f16(a_hi[t], bh, init[t], 0, 0, 0);

        float b0 = fmaxf(fmaxf(acc[0][0], acc[0][1]), fmaxf(acc[0][2], acc[0][3]));
        float b1 = fmaxf(fmaxf(acc[1][0], acc[1][1]), fmaxf(acc[1][2], acc[1][3]));
        float b2 = fmaxf(fmaxf(acc[2][0], acc[2][1]), fmaxf(acc[2][2], acc[2][3]));
        float b3 = fmaxf(fmaxf(acc[3][0], acc[3][1]), fmaxf(acc[3][2], acc[3][3]));
        float best = fmaxf(fmaxf(b0, b1), fmaxf(b2, b3));

        best = fmaxf(best, __shfl_xor(best, 16));
        best = fmaxf(best, __shfl_xor(best, 32));

        if (lane < 16) pm[col] = f32_sortable(best);
    }
}

// ============ reduce1: max over 32 strips per group, keep lowest strip =====
__global__ void som_reduce1_kernel(const uint32_t* __restrict__ pmax,
                                   uint64_t* __restrict__ s2) {
    const int col = blockIdx.x * 256 + threadIdx.x;  // gridDim.x = B/256
    const int sg  = blockIdx.y;                      // 0..SGROUPS-1
    uint32_t best = pmax[(size_t)(sg * SPERG) * B + col];
    int bstrip = sg * SPERG;
#pragma unroll 8
    for (int t = 1; t < SPERG; t++) {
        uint32_t u = pmax[(size_t)(sg * SPERG + t) * B + col];
        if (u > best) { best = u; bstrip = sg * SPERG + t; }  // strict > => lowest strip
    }
    s2[(size_t)sg * B + col] = ((uint64_t)best << 32) | (uint32_t)(~(uint32_t)bstrip);
}

// ============ final: margin-protected exact fp32 rescore + gather ==========
__device__ __forceinline__ void rescore_strip(int strip, int lane,
                                              const float* __restrict__ w,
                                              const float* xr,
                                              uint64_t& best) {
    const int row = strip * 64 + lane;
    const float* wr = w + (size_t)row * D;
    float4 w0 = ((const float4*)wr)[0];
    float4 w1 = ((const float4*)wr)[1];
    float4 w2 = ((const float4*)wr)[2];
    float4 w3 = ((const float4*)wr)[3];
    float4 w4 = ((const float4*)wr)[4];
    float4 w5 = ((const float4*)wr)[5];
    float4 w6 = ((const float4*)wr)[6];
    float4 w7 = ((const float4*)wr)[7];
    const float wf[32] = {w0.x,w0.y,w0.z,w0.w, w1.x,w1.y,w1.z,w1.w,
                          w2.x,w2.y,w2.z,w2.w, w3.x,w3.y,w3.z,w3.w,
                          w4.x,w4.y,w4.z,w4.w, w5.x,w5.y,w5.z,w5.w,
                          w6.x,w6.y,w6.z,w6.w, w7.x,w7.y,w7.z,w7.w};
    float acc = 0.0f, nn = 0.0f;
#pragma unroll
    for (int i = 0; i < D; i++) {
        acc = fmaf(xr[i], wf[i], acc);
        nn  = fmaf(wf[i], wf[i], nn);
    }
    const float score = acc - 0.5f * nn;
    const uint64_t key = ((uint64_t)f32_sortable(score) << 32)
                       | (uint32_t)(~(uint32_t)row);
    if (key > best) best = key;
}

__global__ __launch_bounds__(256)
void som_final_kernel(const uint64_t* __restrict__ s2,
                      const uint32_t* __restrict__ pmax,
                      const float* __restrict__ x,
                      const float* __restrict__ w,
                      const float* __restrict__ grid_flat,
                      float* __restrict__ out) {
    const int wv   = threadIdx.x >> 6;
    const int lane = threadIdx.x & 63;
    const int col  = blockIdx.x * 4 + wv;            // gridDim.x = B/4

    // group keys: lane g < 32 holds group g's (max<<32|~strip)
    uint64_t k = (lane < SGROUPS) ? s2[(size_t)lane * B + col] : 0ull;
    uint64_t kmax = k;
    {
        uint64_t o;
        o = (uint64_t)__shfl_xor((long long)kmax,  1); if (o > kmax) kmax = o;
        o = (uint64_t)__shfl_xor((long long)kmax,  2); if (o > kmax) kmax = o;
        o = (uint64_t)__shfl_xor((long long)kmax,  4); if (o > kmax) kmax = o;
        o = (uint64_t)__shfl_xor((long long)kmax,  8); if (o > kmax) kmax = o;
        o = (uint64_t)__shfl_xor((long long)kmax, 16); if (o > kmax) kmax = o;
        o = (uint64_t)__shfl_xor((long long)kmax, 32); if (o > kmax) kmax = o;
    }
    const float    v1       = sort_decode((uint32_t)(kmax >> 32));
    const uint32_t thresh_u = f32_sortable(v1 - MARGIN);

    // x col into registers (wave-uniform values)
    float xr[D];
    const float4* xp = (const float4*)(x + (size_t)col * D);
#pragma unroll
    for (int i = 0; i < D / 4; i++) {
        float4 v = xp[i];
        xr[4*i+0] = v.x; xr[4*i+1] = v.y; xr[4*i+2] = v.z; xr[4*i+3] = v.w;
    }

    uint64_t best = 0;
    unsigned long long gmask =
        __ballot((lane < SGROUPS) && ((uint32_t)(k >> 32) >= thresh_u));
    while (gmask) {
        const int g = __ffsll(gmask) - 1;
        gmask &= gmask - 1;
        uint32_t u = 0;
        if (lane < SPERG) u = pmax[(size_t)(g * SPERG + lane) * B + col];
        unsigned long long smask = __ballot((lane < SPERG) && (u >= thresh_u));
        while (smask) {
            const int sl = __ffsll(smask) - 1;
            smask &= smask - 1;
            rescore_strip(g * SPERG + sl, lane, w, xr, best);
        }
    }

    // wave argmax over keys (covers all rescored rows)
    {
        uint64_t o;
        o = (uint64_t)__shfl_xor((long long)best,  1); if (o > best) best = o;
        o = (uint64_t)__shfl_xor((long long)best,  2); if (o > best) best = o;
        o = (uint64_t)__shfl_xor((long long)best,  4); if (o > best) best = o;
        o = (uint64_t)__shfl_xor((long long)best,  8); if (o > best) best = o;
        o = (uint64_t)__shfl_xor((long long)best, 16); if (o > best) best = o;
        o = (uint64_t)__shfl_xor((long long)best, 32); if (o > best) best = o;
    }
    if (lane == 0) {
        const uint32_t idx = ~(uint32_t)best;
        ((float2*)out)[col] = ((const float2*)grid_flat)[idx];
    }
}

// ===========================================================================
// Fallback path (round-1, proven correct, needs only 2.36 MB ws)
// ===========================================================================
#define MTILES  128
#define MTILE   (M / MTILES)
#define BTILE   256

__global__ void som_wnorm_kernel(const float* __restrict__ w,
                                 float* __restrict__ wnorm) {
    int t   = blockIdx.x * blockDim.x + threadIdx.x;
    int row = t >> 2;
    int j   = t & 3;
    const float4* p = (const float4*)(w + (size_t)row * D) + j * 2;
    float4 a = p[0];
    float4 b4 = p[1];
    float s = a.x * a.x + a.y * a.y + a.z * a.z + a.w * a.w
            + b4.x * b4.x + b4.y * b4.y + b4.z * b4.z + b4.w * b4.w;
    s += __shfl_xor(s, 1);
    s += __shfl_xor(s, 2);
    if (j == 0) wnorm[row] = 0.5f * s;
}

__global__ __launch_bounds__(BTILE, 8)
void som_score_kernel(const float* __restrict__ x,
                      const float* __restrict__ w,
                      const float* __restrict__ wnorm,
                      float* __restrict__ pscore,
                      int*   __restrict__ pidx) {
    const int bt = blockIdx.x;
    const int mt = blockIdx.y;
    const int b  = bt * BTILE + threadIdx.x;

    float xr[D];
    const float4* xp = (const float4*)(x + (size_t)b * D);
#pragma unroll
    for (int i = 0; i < D / 4; i++) {
        float4 v = xp[i];
        xr[4 * i + 0] = v.x; xr[4 * i + 1] = v.y;
        xr[4 * i + 2] = v.z; xr[4 * i + 3] = v.w;
    }

    const int m0 = mt * MTILE;
    float best = -3.0e38f;
    int   bidx = m0;
#pragma unroll 2
    for (int mm = 0; mm < MTILE; mm++) {
        const int m = m0 + mm;
        const float* __restrict__ wr = w + (size_t)m * D;
        float acc = 0.0f;
#pragma unroll
        for (int i = 0; i < D; i++) acc = fmaf(xr[i], wr[i], acc);
        const float score = acc - wnorm[m];
        if (score > best) { best = score; bidx = m; }
    }
    pscore[(size_t)b * MTILES + mt] = best;
    pidx  [(size_t)b * MTILES + mt] = bidx;
}

__global__ void som_reduce_kernel(const float* __restrict__ pscore,
                                  const int*   __restrict__ pidx,
                                  const float* __restrict__ grid_flat,
                                  float* __restrict__ out) {
    const int b = blockIdx.x * blockDim.x + threadIdx.x;
    const float* ps = pscore + (size_t)b * MTILES;
    const int*   pi = pidx   + (size_t)b * MTILES;
    float best = -3.0e38f;
    int   bidx = 0x7fffffff;
#pragma unroll 4
    for (int t = 0; t < MTILES; t++) {
        const float s  = ps[t];
        const int   id = pi[t];
        if (s > best || (s == best && id < bidx)) { best = s; bidx = id; }
    }
    ((float2*)out)[b] = ((const float2*)grid_flat)[bidx];
}

// ===========================================================================
extern "C" void kernel_launch(void* const* d_in, const int* in_sizes, int n_in,
                              void* d_out, int out_size, void* d_ws, size_t ws_size,
                              hipStream_t stream) {
    const float* x         = (const float*)d_in[0];   // [B, D]
    const float* grid_flat = (const float*)d_in[1];   // [1, M, 2]
    const float* w         = (const float*)d_in[2];   // [1, M, D]
    float* out = (float*)d_out;                       // [B, 2]

    char* ws = (char*)d_ws;
    const size_t XH_OFF = 0;
    const size_t PM_OFF = XH_OFF + (size_t)B * D * sizeof(_Float16);      // 128K
    const size_t S2_OFF = PM_OFF + (size_t)STRIPS * B * sizeof(uint32_t); // +8M
    const size_t NEED   = S2_OFF + (size_t)SGROUPS * B * sizeof(uint64_t);

    if (ws_size >= NEED) {
        _Float16* x_hi = (_Float16*)(ws + XH_OFF);
        uint32_t* pmax = (uint32_t*)(ws + PM_OFF);
        uint64_t* s2   = (uint64_t*)(ws + S2_OFF);

        som_prep_kernel<<<(B * D / 4) / 256, 256, 0, stream>>>(x, x_hi);
        som_screen_kernel<<<STRIPS, 256, 0, stream>>>(w, x_hi, pmax);
        som_reduce1_kernel<<<dim3(B / 256, SGROUPS), 256, 0, stream>>>(pmax, s2);
        som_final_kernel<<<B / 4, 256, 0, stream>>>(s2, pmax, x, w, grid_flat, out);
    } else {
        float* wnorm  = (float*)d_ws;
        float* pscore = wnorm + M;
        int*   pidx   = (int*)(pscore + (size_t)B * MTILES);

        som_wnorm_kernel<<<(M * 4) / 256, 256, 0, stream>>>(w, wnorm);
        dim3 grid1(B / BTILE, MTILES);
        som_score_kernel<<<grid1, BTILE, 0, stream>>>(x, w, wnorm, pscore, pidx);
        som_reduce_kernel<<<B / 256, 256, 0, stream>>>(pscore, pidx, grid_flat, out);
    }
}